// Round 4
// baseline (422.692 us; speedup 1.0000x reference)
//
#include <hip/hip_runtime.h>

#define NNODES 25000
#define NEDGES 400000
#define HDIM   32
#define NHEADS 10
#define NCOLS  320          // HEADS*HDIM
#define NEG    0.2f
#define EPSV   1e-5f
#define NQ     40000        // NEDGES/10 edge-groups (tiles)
#define TPW    4            // tiles per wave
#define GRID_MAIN 2500      // 2500 blocks x 4 waves x 4 tiles = 40000

typedef __bf16 bf16x8 __attribute__((ext_vector_type(8)));
typedef float  f32x4  __attribute__((ext_vector_type(4)));

__device__ __forceinline__ float leaky_f(float v) { return v >= 0.0f ? v : NEG * v; }

__device__ __forceinline__ unsigned pk2(float a, float b) {
  unsigned short ua = __builtin_bit_cast(unsigned short, (__bf16)a);
  unsigned short ub = __builtin_bit_cast(unsigned short, (__bf16)b);
  return (unsigned)ua | ((unsigned)ub << 16);
}
__device__ __forceinline__ float bflo(unsigned p) {
  return __builtin_bit_cast(float, p << 16);
}
__device__ __forceinline__ float bfhi(unsigned p) {
  return __builtin_bit_cast(float, p & 0xffff0000u);
}
__device__ __forceinline__ bf16x8 cvt8(float4 a, float4 b) {
  bf16x8 r;
  r[0] = (__bf16)a.x; r[1] = (__bf16)a.y; r[2] = (__bf16)a.z; r[3] = (__bf16)a.w;
  r[4] = (__bf16)b.x; r[5] = (__bf16)b.y; r[6] = (__bf16)b.z; r[7] = (__bf16)b.w;
  return r;
}

__global__ void agat_init_out(float* __restrict__ out, const float* __restrict__ bias) {
  int i = blockIdx.x * 256 + threadIdx.x;
  if (i < NNODES * HDIM) out[i] = bias[i & (HDIM - 1)];
}

// Wave-autonomous: block = 256 threads = 4 waves. Each wave independently
// processes TPW=4 tiles (16-row M-tiles: 10 real edges + 6 zero pad rows),
// covering ALL 20 column slots (10 heads) itself:
//   - A-frags (xi / xj / ea) gathered per-lane directly from global (no LDS)
//   - W^T in LDS (40KB bf16, XOR-swizzled), 2x ds_read_b128 per slot
//   - logits: MFMA -> leaky -> att fma -> 16-lane shfl_xor butterfly
//   - softmax fully in-register (each lane holds all 10 heads x 4 edges)
//   - messages: packed-bf16 lj * alpha, 4-fma + xor16/32 group-sum
//   - scatter: 5 merged 64-lane f32 atomics per tile
// One __syncthreads per block lifetime (W^T visibility). No other barriers.
__global__ __launch_bounds__(256) void agat_fused(
    const float* __restrict__ x,
    const int*   __restrict__ eidx,
    const float* __restrict__ ea,
    const float* __restrict__ W,
    const float* __restrict__ att,
    const float* __restrict__ gamma,
    const float* __restrict__ beta,
    const float* __restrict__ rmean,
    const float* __restrict__ rvar,
    float*       __restrict__ out)
{
  const int tid = threadIdx.x;
  const int w  = tid >> 6;   // wave 0..3
  const int l  = tid & 63;
  const int lq = l >> 4;     // lane quarter (k-slice / 4-row group)
  const int lr = l & 15;     // row (edge) for A-frags; col-within-slot for B/D

  __shared__ __align__(16) __bf16 wt[NCOLS * 64];   // W^T [c][k] bf16, swizzled, 40KB

  // ---- stage W^T into LDS once: task = (k row 0..63, c4 col-quad 0..79) ----
  for (int task = tid; task < 64 * 80; task += 256) {
    const int k  = task / 80;
    const int c4 = task - k * 80;
    const float4 wv = *(const float4*)(W + k * NCOLS + c4 * 4);
#pragma unroll
    for (int m = 0; m < 4; ++m) {
      const int c = c4 * 4 + m;
      const int off = (c * 128 + k * 2) ^ ((c & 7) << 4);
      *(__bf16*)((char*)wt + off) = (__bf16)((&wv.x)[m]);
    }
  }

  // ---- per-lane constants ----
  float atti[20], attj[20];
#pragma unroll
  for (int t = 0; t < 20; ++t) {
    const int h  = t >> 1;
    const int cc = 16 * (t & 1) + lr;
    atti[t] = att[h * 64 + cc];
    attj[t] = att[h * 64 + 32 + cc];
  }
  float gs[NHEADS], gb[NHEADS];
#pragma unroll
  for (int h = 0; h < NHEADS; ++h) {
    const float inv = rsqrtf(rvar[h] + EPSV);
    gs[h] = inv * gamma[h];
    gb[h] = beta[h] - rmean[h] * inv * gamma[h];
  }

  __syncthreads();   // wt visible; the only block barrier

  const int wave_id = blockIdx.x * 4 + w;
  const f32x4 zero4 = {0.f, 0.f, 0.f, 0.f};

  for (int i = 0; i < TPW; ++i) {
    const int q = wave_id * TPW + i;   // tile id < 40000 by construction

    // ---- gather A-fragments directly (row lr, k-slice lq*8..lq*8+7) ----
    bf16x8 xif, xjf, eaf;
    if (lr < 10) {
      const int e  = q * 10 + lr;
      const int ri = eidx[e];
      const int ci = eidx[NEDGES + e];
      const float* xr = x + ri * HDIM + lq * 8;
      const float* xc = x + ci * HDIM + lq * 8;
      const float* ep = ea + e * HDIM + lq * 8;
      xif = cvt8(*(const float4*)xr, *(const float4*)(xr + 4));
      xjf = cvt8(*(const float4*)xc, *(const float4*)(xc + 4));
      eaf = cvt8(*(const float4*)ep, *(const float4*)(ep + 4));
    } else {
      xif = (bf16x8)(__bf16)0.0f;
      xjf = (bf16x8)(__bf16)0.0f;
      eaf = (bf16x8)(__bf16)0.0f;
    }

    // ---- slot loop: lin_i / lin_j, logits partials, packed lj ----
    float pl[NHEADS][4];               // plog, later overwritten by alpha
#pragma unroll
    for (int h = 0; h < NHEADS; ++h)
#pragma unroll
      for (int p = 0; p < 4; ++p) pl[h][p] = 0.f;
    unsigned ljp[20][2];               // leaky(lin_j) packed bf16 pairs

#pragma unroll
    for (int t = 0; t < 20; ++t) {
      const int cb = 16 * t + lr;      // W^T row (output column)
      const int swz = (cb & 7) << 4;
      const bf16x8 w1 = *(const bf16x8*)((const char*)wt + ((cb * 128 + lq * 16) ^ swz));
      const bf16x8 w2 = *(const bf16x8*)((const char*)wt + ((cb * 128 + 64 + lq * 16) ^ swz));
      const f32x4 c  = __builtin_amdgcn_mfma_f32_16x16x32_bf16(eaf, w2, zero4, 0, 0, 0);
      const f32x4 ai = __builtin_amdgcn_mfma_f32_16x16x32_bf16(xif, w1, c, 0, 0, 0);
      const f32x4 aj = __builtin_amdgcn_mfma_f32_16x16x32_bf16(xjf, w1, c, 0, 0, 0);
      const int h = t >> 1;
      float vj[4];
#pragma unroll
      for (int p = 0; p < 4; ++p) {
        const float vi = leaky_f(ai[p]);
        vj[p] = leaky_f(aj[p]);
        pl[h][p] += vi * atti[t] + vj[p] * attj[t];
      }
      ljp[t][0] = pk2(vj[0], vj[1]);
      ljp[t][1] = pk2(vj[2], vj[3]);
    }

    // ---- 16-lane butterfly: complete the 32-col head dots ----
#pragma unroll
    for (int m = 1; m <= 8; m <<= 1)
#pragma unroll
      for (int h = 0; h < NHEADS; ++h)
#pragma unroll
        for (int p = 0; p < 4; ++p)
          pl[h][p] += __shfl_xor(pl[h][p], m, 64);

    // ---- GroupNorm affine + softmax over heads, fully in-register ----
#pragma unroll
    for (int p = 0; p < 4; ++p) {
      float mx = -1e30f;
#pragma unroll
      for (int h = 0; h < NHEADS; ++h) {
        const float lh = leaky_f(pl[h][p]) * gs[h] + gb[h];
        pl[h][p] = lh;
        mx = fmaxf(mx, lh);
      }
      float s = 0.f;
#pragma unroll
      for (int h = 0; h < NHEADS; ++h) {
        const float e = __expf(pl[h][p] - mx);
        pl[h][p] = e;
        s += e;
      }
      const float inv = 1.f / s;
#pragma unroll
      for (int h = 0; h < NHEADS; ++h) pl[h][p] *= inv;
    }

    // ---- messages: weight, 16-edge group-sum, merged scatter ----
    int ng[5];
#pragma unroll
    for (int g = 0; g < 5; ++g)
      ng[g] = eidx[(2 * g + (lq >> 1)) * NQ + q];   // dest node for this lane's slot

#pragma unroll
    for (int g = 0; g < 5; ++g) {
      float s4[4];
#pragma unroll
      for (int u = 0; u < 4; ++u) {
        const int t = 4 * g + u, h = t >> 1;
        float s = bflo(ljp[t][0]) * pl[h][0] + bfhi(ljp[t][0]) * pl[h][1]
                + bflo(ljp[t][1]) * pl[h][2] + bfhi(ljp[t][1]) * pl[h][3];
        s += __shfl_xor(s, 16, 64);
        s += __shfl_xor(s, 32, 64);    // all lanes hold full 16-row sum
        s4[u] = s;
      }
      const float v01 = (lq & 1) ? s4[1] : s4[0];
      const float v23 = (lq & 1) ? s4[3] : s4[2];
      const float v   = (lq & 2) ? v23 : v01;       // slot t = 4g+lq
      atomicAdd(&out[ng[g] * HDIM + 16 * (lq & 1) + lr], 0.1f * v);
    }
  }
}

extern "C" void kernel_launch(void* const* d_in, const int* in_sizes, int n_in,
                              void* d_out, int out_size, void* d_ws, size_t ws_size,
                              hipStream_t stream) {
  const float* x     = (const float*)d_in[0];
  const int*   eidx  = (const int*)  d_in[1];
  const float* ea    = (const float*)d_in[2];
  const float* W     = (const float*)d_in[3];
  const float* att   = (const float*)d_in[4];
  const float* bias  = (const float*)d_in[5];
  const float* gamma = (const float*)d_in[6];
  const float* beta  = (const float*)d_in[7];
  const float* rmean = (const float*)d_in[8];
  const float* rvar  = (const float*)d_in[9];
  float* out = (float*)d_out;

  agat_init_out<<<(NNODES * HDIM + 255) / 256, 256, 0, stream>>>(out, bias);
  agat_fused<<<GRID_MAIN, 256, 0, stream>>>(x, eidx, ea, W, att, gamma, beta,
                                            rmean, rvar, out);
}

// Round 5
// 343.882 us; speedup vs baseline: 1.2292x; 1.2292x over previous
//
#include <hip/hip_runtime.h>

#define NNODES 25000
#define NEDGES 400000
#define HDIM   32
#define NHEADS 10
#define NCOLS  320          // HEADS*HDIM
#define NEG    0.2f
#define EPSV   1e-5f
#define NQ     40000        // NEDGES/10 edge-groups (16-row tiles, 10 real rows)
#define NB     8            // tiles per round
#define NBATCH 5000         // NQ/NB tile-batches
#define GRID_MAIN 512       // persistent: 2 blocks/CU
#define NITER 10            // 512*10 >= 5000, guarded

typedef __bf16 bf16x8 __attribute__((ext_vector_type(8)));
typedef float  f32x4  __attribute__((ext_vector_type(4)));

__device__ __forceinline__ float leaky_f(float v) { return fmaxf(v, NEG * v); }

__device__ __forceinline__ bf16x8 cvt8(float4 a, float4 b) {
  bf16x8 r;
  r[0] = (__bf16)a.x; r[1] = (__bf16)a.y; r[2] = (__bf16)a.z; r[3] = (__bf16)a.w;
  r[4] = (__bf16)b.x; r[5] = (__bf16)b.y; r[6] = (__bf16)b.z; r[7] = (__bf16)b.w;
  return r;
}

// sum over each 16-lane row; lane 15 of the row ends with the full sum
__device__ __forceinline__ float dpp_red16(float x) {
  int xi = __builtin_bit_cast(int, x);
  x += __builtin_bit_cast(float, __builtin_amdgcn_update_dpp(0, xi, 0x111, 0xf, 0xf, true));
  xi = __builtin_bit_cast(int, x);
  x += __builtin_bit_cast(float, __builtin_amdgcn_update_dpp(0, xi, 0x112, 0xf, 0xf, true));
  xi = __builtin_bit_cast(int, x);
  x += __builtin_bit_cast(float, __builtin_amdgcn_update_dpp(0, xi, 0x114, 0xf, 0xf, true));
  xi = __builtin_bit_cast(int, x);
  x += __builtin_bit_cast(float, __builtin_amdgcn_update_dpp(0, xi, 0x118, 0xf, 0xf, true));
  return x;
}

__global__ void agat_init_out(float* __restrict__ out, const float* __restrict__ bias) {
  int i = blockIdx.x * 256 + threadIdx.x;
  if (i < NNODES * HDIM) out[i] = bias[i & (HDIM - 1)];
}

// Block = 640 threads = 10 waves; wave w owns head w (cols 32w..32w+31 = slots u=0,1).
// Per round (NB=8 tiles): pass1 computes GN-affined logits -> sm[buf] (1 ds_write_b128
// per wave per tile, DPP reduce on VALU pipe); ONE barrier; pass2 softmaxes redundantly
// per wave (broadcast LDS reads), bpermute-redistributes alpha, recomputes the j-side
// (A-frags gathered per-lane from global, L2-hot), one 32-lane atomic per (tile,wave).
// sm is double-buffered so a single barrier per round is sufficient.
__global__ __launch_bounds__(640, 5) void agat_fused(
    const float* __restrict__ x,
    const int*   __restrict__ eidx,
    const float* __restrict__ ea,
    const float* __restrict__ W,
    const float* __restrict__ att,
    const float* __restrict__ gamma,
    const float* __restrict__ beta,
    const float* __restrict__ rmean,
    const float* __restrict__ rvar,
    float*       __restrict__ out)
{
  const int tid = threadIdx.x;
  const int w  = tid >> 6;   // wave 0..9 = head
  const int l  = tid & 63;
  const int lq = l >> 4;     // quarter: k-slice (A), 4-row group (D)
  const int lr = l & 15;     // row (A), col-within-slot (B/D)

  __shared__ __align__(16) float sm[2 * NB * NHEADS * 16];  // [buf][nt][head][row]

  // ---- per-wave constants: W frags (2 slots), att, GroupNorm affine ----
  bf16x8 wf1[2], wf2[2];
#pragma unroll
  for (int u = 0; u < 2; ++u) {
    const int c = 32 * w + 16 * u + lr;
#pragma unroll
    for (int j = 0; j < 8; ++j) {
      const int k = lq * 8 + j;
      wf1[u][j] = (__bf16)W[k * NCOLS + c];
      wf2[u][j] = (__bf16)W[(32 + k) * NCOLS + c];
    }
  }
  float atti[2], attj[2];
#pragma unroll
  for (int u = 0; u < 2; ++u) {
    atti[u] = att[w * 64 + 16 * u + lr];
    attj[u] = att[w * 64 + 32 + 16 * u + lr];
  }
  const float ivr = rsqrtf(rvar[w] + EPSV);
  const float gsc = ivr * gamma[w];
  const float gof = beta[w] - rmean[w] * ivr * gamma[w];

  const f32x4 zero4 = {0.f, 0.f, 0.f, 0.f};

  for (int it = 0; it < NITER; ++it) {
    const int B = it * GRID_MAIN + blockIdx.x;
    const bool active = (B < NBATCH);
    float* smb = sm + (it & 1) * (NB * NHEADS * 16);

    if (active) {
      // ---------------- pass 1: logits ----------------
#pragma unroll
      for (int nt = 0; nt < NB; ++nt) {
        const int q = B * NB + nt;
        bf16x8 xif = (bf16x8)(__bf16)0.0f;
        bf16x8 xjf = (bf16x8)(__bf16)0.0f;
        bf16x8 eaf = (bf16x8)(__bf16)0.0f;
        if (lr < 10) {
          const int e  = q * 10 + lr;
          const int ri = eidx[e];
          const int ci = eidx[NEDGES + e];
          const float* xr = x + ri * HDIM + lq * 8;
          const float* xc = x + ci * HDIM + lq * 8;
          const float* ep = ea + e * HDIM + lq * 8;
          xif = cvt8(*(const float4*)xr, *(const float4*)(xr + 4));
          xjf = cvt8(*(const float4*)xc, *(const float4*)(xc + 4));
          eaf = cvt8(*(const float4*)ep, *(const float4*)(ep + 4));
        }
        float plog[4] = {0.f, 0.f, 0.f, 0.f};
#pragma unroll
        for (int u = 0; u < 2; ++u) {
          const f32x4 c  = __builtin_amdgcn_mfma_f32_16x16x32_bf16(eaf, wf2[u], zero4, 0, 0, 0);
          const f32x4 ai = __builtin_amdgcn_mfma_f32_16x16x32_bf16(xif, wf1[u], c, 0, 0, 0);
          const f32x4 aj = __builtin_amdgcn_mfma_f32_16x16x32_bf16(xjf, wf1[u], c, 0, 0, 0);
#pragma unroll
          for (int p = 0; p < 4; ++p)
            plog[p] += leaky_f(ai[p]) * atti[u] + leaky_f(aj[p]) * attj[u];
        }
#pragma unroll
        for (int p = 0; p < 4; ++p) plog[p] = dpp_red16(plog[p]);
        if (lr == 15) {           // lane 15 of each quarter holds the 32-col total
          f32x4 v;
#pragma unroll
          for (int p = 0; p < 4; ++p) v[p] = leaky_f(plog[p]) * gsc + gof;
          *(f32x4*)(smb + nt * 160 + w * 16 + lq * 4) = v;
        }
      }
    }

    __syncthreads();   // the only barrier per round (sm dbuf makes it sufficient)

    if (active) {
      // ---------------- pass 2: softmax + messages + scatter ----------------
#pragma unroll
      for (int nt = 0; nt < NB; ++nt) {
        const int q = B * NB + nt;
        // re-gather j-side fragments (L2-hot)
        bf16x8 xjf = (bf16x8)(__bf16)0.0f;
        bf16x8 eaf = (bf16x8)(__bf16)0.0f;
        if (lr < 10) {
          const int e  = q * 10 + lr;
          const int ci = eidx[NEDGES + e];
          const float* xc = x + ci * HDIM + lq * 8;
          const float* ep = ea + e * HDIM + lq * 8;
          xjf = cvt8(*(const float4*)xc, *(const float4*)(xc + 4));
          eaf = cvt8(*(const float4*)ep, *(const float4*)(ep + 4));
        }

        // in-wave softmax for row_s = lq*4 + (lr&3)  (4-fold replicated)
        const float* base = smb + nt * 160 + (lq * 4 + (lr & 3));
        float eh[NHEADS];
#pragma unroll
        for (int h = 0; h < NHEADS; ++h) eh[h] = base[h * 16];
        float mx = fmaxf(fmaxf(fmaxf(eh[0], eh[1]), fmaxf(eh[2], eh[3])),
                         fmaxf(fmaxf(eh[4], eh[5]),
                               fmaxf(fmaxf(eh[6], eh[7]), fmaxf(eh[8], eh[9]))));
        float s = 0.f;
#pragma unroll
        for (int h = 0; h < NHEADS; ++h) { eh[h] = __expf(eh[h] - mx); s += eh[h]; }
        const float inv = 1.0f / s;

        // expose alpha[u_l], alpha[u_l+4], alpha[8+(u_l&1)] for bpermute pulls
        const int u_l = lr >> 2;
        const float a01 = (u_l & 1) ? eh[1] : eh[0];
        const float a23 = (u_l & 1) ? eh[3] : eh[2];
        const float av_a = ((u_l & 2) ? a23 : a01) * inv;
        const float b01 = (u_l & 1) ? eh[5] : eh[4];
        const float b23 = (u_l & 1) ? eh[7] : eh[6];
        const float av_b = ((u_l & 2) ? b23 : b01) * inv;
        const float av_c = ((u_l & 1) ? eh[9] : eh[8]) * inv;

        // wave-uniform pick of the exposure register holding head w
        const float avsrc = (w < 4) ? av_a : ((w < 8) ? av_b : av_c);
        float alf[4];
#pragma unroll
        for (int p = 0; p < 4; ++p) {
          const int src = (l & 48) + p + 4 * (w & 3);
          alf[p] = __builtin_bit_cast(float,
              __builtin_amdgcn_ds_bpermute(src << 2, __builtin_bit_cast(int, avsrc)));
        }

        // j-side recompute + weighting + 16-row reduce
        float st[2];
#pragma unroll
        for (int u = 0; u < 2; ++u) {
          const f32x4 c  = __builtin_amdgcn_mfma_f32_16x16x32_bf16(eaf, wf2[u], zero4, 0, 0, 0);
          const f32x4 aj = __builtin_amdgcn_mfma_f32_16x16x32_bf16(xjf, wf1[u], c, 0, 0, 0);
          float t = 0.f;
#pragma unroll
          for (int p = 0; p < 4; ++p) t += leaky_f(aj[p]) * alf[p];  // pad rows: aj==0
          t += __shfl_xor(t, 16, 64);
          t += __shfl_xor(t, 32, 64);
          st[u] = t;
        }

        // scatter: slot a = w*NQ+q consumes this (tile, head); dest is wave-uniform
        const int n = eidx[w * NQ + q];
        if (l < 32) {
          const float v = (l >> 4) ? st[1] : st[0];
          atomicAdd(&out[n * HDIM + l], 0.1f * v);
        }
      }
    }
  }
}

extern "C" void kernel_launch(void* const* d_in, const int* in_sizes, int n_in,
                              void* d_out, int out_size, void* d_ws, size_t ws_size,
                              hipStream_t stream) {
  const float* x     = (const float*)d_in[0];
  const int*   eidx  = (const int*)  d_in[1];
  const float* ea    = (const float*)d_in[2];
  const float* W     = (const float*)d_in[3];
  const float* att   = (const float*)d_in[4];
  const float* bias  = (const float*)d_in[5];
  const float* gamma = (const float*)d_in[6];
  const float* beta  = (const float*)d_in[7];
  const float* rmean = (const float*)d_in[8];
  const float* rvar  = (const float*)d_in[9];
  float* out = (float*)d_out;

  agat_init_out<<<(NNODES * HDIM + 255) / 256, 256, 0, stream>>>(out, bias);
  agat_fused<<<GRID_MAIN, 640, 0, stream>>>(x, eidx, ea, W, att, gamma, beta,
                                            rmean, rvar, out);
}